// Round 3
// baseline (501.337 us; speedup 1.0000x reference)
//
#include <hip/hip_runtime.h>

#define HH 160
#define WW 160

typedef __attribute__((ext_vector_type(8))) short bf16x8;
typedef __attribute__((ext_vector_type(4))) float f32x4;

__device__ __forceinline__ unsigned short f32_to_bf16_rne(float f) {
    unsigned u = __float_as_uint(f);
    unsigned r = (u + 0x7FFFu + ((u >> 16) & 1u)) >> 16;
    return (unsigned short)r;
}
__device__ __forceinline__ float bf16_to_f32(unsigned short h) {
    return __uint_as_float(((unsigned)h) << 16);
}

// ---------------------------------------------------------------------------
// Prep: pack pw_w[2] into MFMA B-fragment layout, bf16 hi/lo split.
// frag = (((b*9+kk)*4 + ct)*2 + kh)*2 + comp ; per frag 64 lanes x 8 u16.
// Element (lane,j): B[k=kh*32+(lane>>4)*8+j][n=ct*16+(lane&15)], W[cp][c]=pw[(c*9+kk)*64+cp]
// ---------------------------------------------------------------------------
__global__ __launch_bounds__(256) void prep_w_kernel(const float* __restrict__ pw0,
                                                     const float* __restrict__ pw1,
                                                     unsigned short* __restrict__ wF) {
    int idx = blockIdx.x * 256 + threadIdx.x;   // 288*64 = 18432
    if (idx >= 18432) return;
    int lane = idx & 63;
    int frag = idx >> 6;
    int comp = frag & 1;
    int kh   = (frag >> 1) & 1;
    int ct   = (frag >> 2) & 3;
    int t    = frag >> 4;             // b*9+kk
    int bb   = t / 9;
    int kk   = t - bb * 9;
    const float* pw = bb ? pw1 : pw0;
    int c = ct * 16 + (lane & 15);
    bf16x8 pack;
    #pragma unroll
    for (int j = 0; j < 8; ++j) {
        int cp = kh * 32 + (lane >> 4) * 8 + j;
        float v = pw[(c * 9 + kk) * 64 + cp];
        unsigned short hb = f32_to_bf16_rne(v);
        if (comp == 0) pack[j] = (short)hb;
        else           pack[j] = (short)f32_to_bf16_rne(v - bf16_to_f32(hb));
    }
    *(bf16x8*)&wF[frag * 512 + lane * 8] = pack;
}

// ---------------------------------------------------------------------------
// Fused kernel. Tile = 2 h-rows x 32 w = 64 px, all 64 channels, 4 waves.
// Wave wid owns M-tile px [wid*16, wid*16+16) (same h-row) x ALL 64 channels.
// Register-lean: afr = 4 frags (16 VGPR), bfr streamed per (kk,ct), kern f32x4.
// x read direct from global (no LDS staging, no per-di barriers).
// ---------------------------------------------------------------------------
__global__ __launch_bounds__(256, 3) void fused_kernel(
    const float* __restrict__ y,   const float* __restrict__ x,
    const float* __restrict__ dw0, const float* __restrict__ g0,
    const float* __restrict__ bb0, const float* __restrict__ m0,
    const float* __restrict__ v0,  const float* __restrict__ pwb0,
    const float* __restrict__ dw1, const float* __restrict__ g1,
    const float* __restrict__ bb1, const float* __restrict__ m1,
    const float* __restrict__ v1,  const float* __restrict__ pwb1,
    const float* __restrict__ ng,  const float* __restrict__ nbb,
    const float* __restrict__ nm,  const float* __restrict__ nv,
    const unsigned short* __restrict__ wF, float* __restrict__ out)
{
    __shared__ unsigned short t_hi[64 * 72];   // [px][cp], row 144B, chunk-XOR swizzle
    __shared__ unsigned short t_lo[64 * 72];
    __shared__ float dwl[2 * 576];
    __shared__ float pwbl[2 * 576];
    __shared__ float scb[2 * 64], shb[2 * 64], nscl[64], nshl[64];

    const int tid  = threadIdx.x;
    const int lane = tid & 63;
    const int wid  = tid >> 6;
    const int cl   = lane & 15;
    const int pg   = lane >> 4;

    // bijective XCD swizzle: 1600 = 8 * 200 -> vertical neighbors share an XCD's L2
    const int bid0 = blockIdx.x;
    const int bid  = (bid0 & 7) * 200 + (bid0 >> 3);
    const int n    = bid / 400;
    const int rem  = bid - n * 400;
    const int ht   = rem / 5;
    const int wt   = rem - ht * 5;
    const int h    = ht * 2;
    const int w0   = wt * 32;

    const float* ybase = y + (size_t)n * (64 * HH * WW);
    const float* xbase = x + (size_t)n * (64 * HH * WW);

    for (int e = tid; e < 576; e += 256) {
        dwl[e] = dw0[e];  dwl[576 + e] = dw1[e];
        pwbl[e] = pwb0[e]; pwbl[576 + e] = pwb1[e];
    }
    if (tid < 64) {
        float s0 = g0[tid] * rsqrtf(v0[tid] + 1e-5f);
        scb[tid] = s0;      shb[tid] = bb0[tid] - m0[tid] * s0;
        float s1 = g1[tid] * rsqrtf(v1[tid] + 1e-5f);
        scb[64 + tid] = s1; shb[64 + tid] = bb1[tid] - m1[tid] * s1;
        float sn = ng[tid] * rsqrtf(nv[tid] + 1e-5f);
        nscl[tid] = sn;     nshl[tid] = nbb[tid] - nm[tid] * sn;
    }
    __syncthreads();

    float outacc[4][4];   // [ct][rr]
    #pragma unroll
    for (int ct = 0; ct < 4; ++ct)
        #pragma unroll
        for (int rr = 0; rr < 4; ++rr) outacc[ct][rr] = 0.f;

    #pragma unroll
    for (int b = 0; b < 2; ++b) {
        const int r = b + 1;
        if (b) __syncthreads();   // all waves done reading t of prev branch

        // ---- depthwise conv + BN + ReLU -> t (bf16 hi/lo, swizzled) ------
        {
            const int px = tid & 63;
            const int rl = px >> 5, wl = px & 31;
            #pragma unroll
            for (int it = 0; it < 2; ++it) {
                const int chunk = wid + it * 4;    // 0..7
                const int cp0 = chunk * 8;
                bf16x8 h8, l8;
                #pragma unroll
                for (int jc = 0; jc < 8; ++jc) {
                    const int cp = cp0 + jc;
                    float a = 0.f;
                    #pragma unroll
                    for (int i = 0; i < 3; ++i) {
                        const int hr = h + rl + (i - 1) * r;
                        const bool hok = (unsigned)hr < (unsigned)HH;
                        const float* yr = ybase + ((size_t)cp * HH + hr) * WW;
                        #pragma unroll
                        for (int j = 0; j < 3; ++j) {
                            const int wc = w0 + wl + (j - 1) * r;
                            float yv = (hok && (unsigned)wc < (unsigned)WW) ? yr[wc] : 0.f;
                            a = fmaf(yv, dwl[b * 576 + cp * 9 + i * 3 + j], a);
                        }
                    }
                    float tv = fmaxf(fmaf(a, scb[b * 64 + cp], shb[b * 64 + cp]), 0.f);
                    unsigned short hb = f32_to_bf16_rne(tv);
                    float lo = tv - bf16_to_f32(hb);
                    h8[jc] = (short)hb;
                    l8[jc] = (short)f32_to_bf16_rne(lo);
                }
                const int phys = chunk ^ ((px >> 1) & 7);
                *(bf16x8*)&t_hi[px * 72 + phys * 8] = h8;
                *(bf16x8*)&t_lo[px * 72 + phys * 8] = l8;
            }
        }
        __syncthreads();

        // ---- A fragments: this wave's 16 px, full K=64, hi+lo (16 VGPRs) -
        bf16x8 afr[2][2];
        {
            const int px = wid * 16 + cl;
            #pragma unroll
            for (int kh = 0; kh < 2; ++kh) {
                const int chunk = kh * 4 + pg;
                const int phys  = chunk ^ ((px >> 1) & 7);
                afr[kh][0] = *(const bf16x8*)&t_hi[px * 72 + phys * 8];
                afr[kh][1] = *(const bf16x8*)&t_lo[px * 72 + phys * 8];
            }
        }

        const int wrow = wid >> 1;             // tile row of this wave's px
        const int wcol = (wid & 1) * 16;       // tile col base
        #pragma unroll
        for (int di = 0; di < 3; ++di) {
            const int xrow = h + wrow + (di - 1) * r;
            if ((unsigned)xrow >= (unsigned)HH) continue;   // x==0 -> no contribution
            #pragma unroll
            for (int dj = 0; dj < 3; ++dj) {
                const int kk  = di * 3 + dj;
                const int xc0 = w0 + wcol + pg * 4 + (dj - 1) * r;
                const unsigned short* wfb = wF + (size_t)((b * 9 + kk) * 16) * 512;
                #pragma unroll
                for (int ct = 0; ct < 4; ++ct) {
                    bf16x8 bfr[2][2];
                    #pragma unroll
                    for (int kh = 0; kh < 2; ++kh)
                        #pragma unroll
                        for (int cm = 0; cm < 2; ++cm)
                            bfr[kh][cm] = *(const bf16x8*)&wfb[(ct * 4 + kh * 2 + cm) * 512 + lane * 8];

                    const int c = ct * 16 + cl;
                    const float bv = pwbl[b * 576 + c * 9 + kk];
                    f32x4 kern = {bv, bv, bv, bv};
                    // bf16x3: hi*hi + lo*hi + hi*lo
                    #pragma unroll
                    for (int p = 0; p < 3; ++p) {
                        const int ac = (p == 2) ? 1 : 0;
                        const int bc = (p == 1) ? 1 : 0;
                        #pragma unroll
                        for (int kh = 0; kh < 2; ++kh)
                            kern = __builtin_amdgcn_mfma_f32_16x16x32_bf16(
                                afr[kh][ac], bfr[kh][bc], kern, 0, 0, 0);
                    }

                    const float* xp = xbase + ((size_t)c * HH + xrow) * WW + xc0;
                    if ((unsigned)xc0 <= (unsigned)(WW - 4)) {
                        f32x4 xv;
                        __builtin_memcpy(&xv, xp, 16);   // align-4 dwordx4
                        #pragma unroll
                        for (int rr = 0; rr < 4; ++rr)
                            outacc[ct][rr] = fmaf(kern[rr], xv[rr], outacc[ct][rr]);
                    } else {
                        #pragma unroll
                        for (int rr = 0; rr < 4; ++rr) {
                            const int xc = xc0 + rr;
                            float xv = ((unsigned)xc < (unsigned)WW) ? xp[rr] : 0.f;
                            outacc[ct][rr] = fmaf(kern[rr], xv, outacc[ct][rr]);
                        }
                    }
                }
            }
        }
    }

    // ---- epilogue: final BN + ReLU, direct coalesced float4 stores -------
    {
        const int hrow = h + (wid >> 1);
        const int wc0  = w0 + (wid & 1) * 16 + pg * 4;
        #pragma unroll
        for (int ct = 0; ct < 4; ++ct) {
            const int c = ct * 16 + cl;
            const float sn = nscl[c], sh = nshl[c];
            f32x4 o;
            #pragma unroll
            for (int rr = 0; rr < 4; ++rr)
                o[rr] = fmaxf(fmaf(outacc[ct][rr], sn, sh), 0.f);
            *(f32x4*)&out[(((size_t)n * 64 + c) * HH + hrow) * WW + wc0] = o;
        }
    }
}

extern "C" void kernel_launch(void* const* d_in, const int* in_sizes, int n_in,
                              void* d_out, int out_size, void* d_ws, size_t ws_size,
                              hipStream_t stream) {
    const float* y    = (const float*)d_in[0];
    const float* x    = (const float*)d_in[1];
    const float* dw0  = (const float*)d_in[2];
    const float* g0   = (const float*)d_in[3];
    const float* b0   = (const float*)d_in[4];
    const float* m0   = (const float*)d_in[5];
    const float* v0   = (const float*)d_in[6];
    const float* pw0  = (const float*)d_in[7];
    const float* pwb0 = (const float*)d_in[8];
    const float* dw1  = (const float*)d_in[9];
    const float* g1   = (const float*)d_in[10];
    const float* b1   = (const float*)d_in[11];
    const float* m1   = (const float*)d_in[12];
    const float* v1   = (const float*)d_in[13];
    const float* pw1  = (const float*)d_in[14];
    const float* pwb1 = (const float*)d_in[15];
    const float* ng   = (const float*)d_in[16];
    const float* nb   = (const float*)d_in[17];
    const float* nm   = (const float*)d_in[18];
    const float* nv   = (const float*)d_in[19];

    unsigned short* wF = (unsigned short*)d_ws;   // 294912 B

    prep_w_kernel<<<72, 256, 0, stream>>>(pw0, pw1, wF);
    fused_kernel<<<1600, 256, 0, stream>>>(y, x,
                                           dw0, g0, b0, m0, v0, pwb0,
                                           dw1, g1, b1, m1, v1, pwb1,
                                           ng, nb, nm, nv, wF, (float*)d_out);
}

// Round 4
// 489.627 us; speedup vs baseline: 1.0239x; 1.0239x over previous
//
#include <hip/hip_runtime.h>

#define HH 160
#define WW 160

typedef __attribute__((ext_vector_type(8))) short bf16x8;
typedef __attribute__((ext_vector_type(4))) float f32x4;

static __device__ __forceinline__ unsigned short f32_to_bf16_rne(float f) {
    unsigned u = __float_as_uint(f);
    unsigned r = (u + 0x7FFFu + ((u >> 16) & 1u)) >> 16;
    return (unsigned short)r;
}
static __device__ __forceinline__ float bf16_to_f32(unsigned short h) {
    return __uint_as_float(((unsigned)h) << 16);
}

// ---------------------------------------------------------------------------
// Prep: pack pw_w[2] into MFMA B-fragment layout, bf16 hi/lo split.
// frag = (((b*9+kk)*4 + ct)*2 + kh)*2 + comp ; per frag 64 lanes x 8 u16.
// Element (lane,j): B[k=kh*32+(lane>>4)*8+j][n=ct*16+(lane&15)], W[cp][c]=pw[(c*9+kk)*64+cp]
// ---------------------------------------------------------------------------
__global__ __launch_bounds__(256) void prep_w_kernel(const float* __restrict__ pw0,
                                                     const float* __restrict__ pw1,
                                                     unsigned short* __restrict__ wF) {
    int idx = blockIdx.x * 256 + threadIdx.x;   // 288*64 = 18432
    if (idx >= 18432) return;
    int lane = idx & 63;
    int frag = idx >> 6;
    int comp = frag & 1;
    int kh   = (frag >> 1) & 1;
    int ct   = (frag >> 2) & 3;
    int t    = frag >> 4;             // b*9+kk
    int bb   = t / 9;
    int kk   = t - bb * 9;
    const float* pw = bb ? pw1 : pw0;
    int c = ct * 16 + (lane & 15);
    bf16x8 pack;
    #pragma unroll
    for (int j = 0; j < 8; ++j) {
        int cp = kh * 32 + (lane >> 4) * 8 + j;
        float v = pw[(c * 9 + kk) * 64 + cp];
        unsigned short hb = f32_to_bf16_rne(v);
        if (comp == 0) pack[j] = (short)hb;
        else           pack[j] = (short)f32_to_bf16_rne(v - bf16_to_f32(hb));
    }
    *(bf16x8*)&wF[frag * 512 + lane * 8] = pack;
}

// ---------------------------------------------------------------------------
// Fused kernel. Block = 4 h-rows x 32 w = 128 px, all 64 channels, 4 waves.
// Wave wid owns one row (32 px = 2 M-frags) x all 64 output channels.
// B-fragments streamed from global/L2 with explicit register double-buffer
// across the 36 unrolled (kk,ct) steps; 12 MFMAs per 4-load group.
// ---------------------------------------------------------------------------
__global__ __launch_bounds__(256, 2) void fused_kernel(
    const float* __restrict__ y,   const float* __restrict__ x,
    const float* __restrict__ dw0, const float* __restrict__ g0,
    const float* __restrict__ bb0, const float* __restrict__ m0,
    const float* __restrict__ v0,  const float* __restrict__ pwb0,
    const float* __restrict__ dw1, const float* __restrict__ g1,
    const float* __restrict__ bb1, const float* __restrict__ m1,
    const float* __restrict__ v1,  const float* __restrict__ pwb1,
    const float* __restrict__ ng,  const float* __restrict__ nbb,
    const float* __restrict__ nm,  const float* __restrict__ nv,
    const unsigned short* __restrict__ wF, float* __restrict__ out)
{
    __shared__ unsigned short t_hi[128 * 72];   // [px][cp], chunk-XOR swizzle
    __shared__ unsigned short t_lo[128 * 72];
    __shared__ float dwl[2 * 576];
    __shared__ float pwbl[2 * 576];
    __shared__ float scb[2 * 64], shb[2 * 64], nscl[64], nshl[64];

    const int tid  = threadIdx.x;
    const int lane = tid & 63;
    const int wid  = tid >> 6;
    const int cl   = lane & 15;
    const int pg   = lane >> 4;

    // bijective XCD swizzle: 800 = 8 * 100
    const int bid0 = blockIdx.x;
    const int bid  = (bid0 & 7) * 100 + (bid0 >> 3);
    const int n    = bid / 200;
    const int rem  = bid - n * 200;
    const int ht   = rem / 5;
    const int wt   = rem - ht * 5;
    const int h    = ht * 4;
    const int w0   = wt * 32;

    const float* ybase = y + (size_t)n * (64 * HH * WW);
    const float* xbase = x + (size_t)n * (64 * HH * WW);

    for (int e = tid; e < 576; e += 256) {
        dwl[e] = dw0[e];  dwl[576 + e] = dw1[e];
        pwbl[e] = pwb0[e]; pwbl[576 + e] = pwb1[e];
    }
    if (tid < 64) {
        float s0 = g0[tid] * rsqrtf(v0[tid] + 1e-5f);
        scb[tid] = s0;      shb[tid] = bb0[tid] - m0[tid] * s0;
        float s1 = g1[tid] * rsqrtf(v1[tid] + 1e-5f);
        scb[64 + tid] = s1; shb[64 + tid] = bb1[tid] - m1[tid] * s1;
        float sn = ng[tid] * rsqrtf(nv[tid] + 1e-5f);
        nscl[tid] = sn;     nshl[tid] = nbb[tid] - nm[tid] * sn;
    }
    __syncthreads();

    float outacc[2][4][4];   // [mt][ct][rr]
    #pragma unroll
    for (int mt = 0; mt < 2; ++mt)
        #pragma unroll
        for (int ct = 0; ct < 4; ++ct)
            #pragma unroll
            for (int rr = 0; rr < 4; ++rr) outacc[mt][ct][rr] = 0.f;

    #pragma unroll
    for (int b = 0; b < 2; ++b) {
        const int r = b + 1;

        // ---- depthwise conv + BN + ReLU -> t (bf16 hi/lo, swizzled) ------
        // (prev branch's afr reads are done: barrier after afr load below)
        {
            const int px = tid & 127;
            const int rl = px >> 5, wl = px & 31;
            const int cb = (tid >> 7) * 4;
            #pragma unroll
            for (int it = 0; it < 4; ++it) {
                const int chunk = cb + it;           // 0..7
                const int cp0 = chunk * 8;
                bf16x8 h8, l8;
                #pragma unroll
                for (int jc = 0; jc < 8; ++jc) {
                    const int cp = cp0 + jc;
                    float a = 0.f;
                    #pragma unroll
                    for (int i = 0; i < 3; ++i) {
                        const int hr = h + rl + (i - 1) * r;
                        const bool hok = (unsigned)hr < (unsigned)HH;
                        const float* yr = ybase + ((size_t)cp * HH + hr) * WW;
                        #pragma unroll
                        for (int j = 0; j < 3; ++j) {
                            const int wc = w0 + wl + (j - 1) * r;
                            float yv = (hok && (unsigned)wc < (unsigned)WW) ? yr[wc] : 0.f;
                            a = fmaf(yv, dwl[b * 576 + cp * 9 + i * 3 + j], a);
                        }
                    }
                    float tv = fmaxf(fmaf(a, scb[b * 64 + cp], shb[b * 64 + cp]), 0.f);
                    unsigned short hb = f32_to_bf16_rne(tv);
                    h8[jc] = (short)hb;
                    l8[jc] = (short)f32_to_bf16_rne(tv - bf16_to_f32(hb));
                }
                const int phys = chunk ^ ((px >> 1) & 7);
                *(bf16x8*)&t_hi[px * 72 + phys * 8] = h8;
                *(bf16x8*)&t_lo[px * 72 + phys * 8] = l8;
            }
        }
        __syncthreads();

        // ---- A fragments: 32 px (2 M-frags), K=64, hi+lo (32 VGPRs) ------
        bf16x8 afr[2][2][2];
        #pragma unroll
        for (int mt = 0; mt < 2; ++mt) {
            const int px = wid * 32 + mt * 16 + cl;
            #pragma unroll
            for (int kh = 0; kh < 2; ++kh) {
                const int chunk = kh * 4 + pg;
                const int phys  = chunk ^ ((px >> 1) & 7);
                afr[mt][kh][0] = *(const bf16x8*)&t_hi[px * 72 + phys * 8];
                afr[mt][kh][1] = *(const bf16x8*)&t_lo[px * 72 + phys * 8];
            }
        }
        __syncthreads();   // afr in regs everywhere -> next branch may overwrite t

        // ---- GEMM + unfold contraction, reg-dbuf'd B stream --------------
        const unsigned short* wfB = wF + (size_t)(b * 9) * 16 * 512;
        bf16x8 bbuf[2][4];
        #pragma unroll
        for (int f = 0; f < 4; ++f)
            bbuf[0][f] = *(const bf16x8*)&wfB[f * 512 + lane * 8];
        const int xrow0 = h + wid;

        #pragma unroll
        for (int q = 0; q < 36; ++q) {
            const int kk = q >> 2, ct = q & 3, cur = q & 1;
            const int di = kk / 3, dj = kk - di * 3;
            // prefetch next step's 4 B-fragments into the other buffer
            if (q < 35) {
                const unsigned short* wfn = wfB + (size_t)(q + 1) * 4 * 512;
                #pragma unroll
                for (int f = 0; f < 4; ++f)
                    bbuf[cur ^ 1][f] = *(const bf16x8*)&wfn[f * 512 + lane * 8];
            }
            const int c = ct * 16 + cl;
            const float bv = pwbl[b * 576 + c * 9 + kk];
            f32x4 k0 = {bv, bv, bv, bv};
            f32x4 k1 = k0;
            // bf16x3: hi*hi + hi*lo + lo*hi
            #pragma unroll
            for (int p = 0; p < 3; ++p) {
                const int ac = (p == 2) ? 1 : 0;
                const int bc = (p == 1) ? 1 : 0;
                #pragma unroll
                for (int kh = 0; kh < 2; ++kh) {
                    k0 = __builtin_amdgcn_mfma_f32_16x16x32_bf16(
                        afr[0][kh][ac], bbuf[cur][kh * 2 + bc], k0, 0, 0, 0);
                    k1 = __builtin_amdgcn_mfma_f32_16x16x32_bf16(
                        afr[1][kh][ac], bbuf[cur][kh * 2 + bc], k1, 0, 0, 0);
                }
            }
            const int xrow = xrow0 + (di - 1) * r;
            if ((unsigned)xrow < (unsigned)HH) {
                const float* xrp = xbase + ((size_t)c * HH + xrow) * WW;
                #pragma unroll
                for (int mt = 0; mt < 2; ++mt) {
                    const int xc0 = w0 + mt * 16 + pg * 4 + (dj - 1) * r;
                    const f32x4 kv = mt ? k1 : k0;
                    if ((unsigned)xc0 <= (unsigned)(WW - 4)) {
                        f32x4 xv;
                        __builtin_memcpy(&xv, xrp + xc0, 16);
                        #pragma unroll
                        for (int rr = 0; rr < 4; ++rr)
                            outacc[mt][ct][rr] = fmaf(kv[rr], xv[rr], outacc[mt][ct][rr]);
                    } else {
                        #pragma unroll
                        for (int rr = 0; rr < 4; ++rr) {
                            const int xc = xc0 + rr;
                            float xv = ((unsigned)xc < (unsigned)WW) ? xrp[xc] : 0.f;
                            outacc[mt][ct][rr] = fmaf(kv[rr], xv, outacc[mt][ct][rr]);
                        }
                    }
                }
            }
        }
    }

    // ---- epilogue: final BN + ReLU, coalesced float4 stores --------------
    {
        const int hrow = h + wid;
        #pragma unroll
        for (int mt = 0; mt < 2; ++mt) {
            const int wc0 = w0 + mt * 16 + pg * 4;
            #pragma unroll
            for (int ct = 0; ct < 4; ++ct) {
                const int c = ct * 16 + cl;
                const float sn = nscl[c], sh = nshl[c];
                f32x4 o;
                #pragma unroll
                for (int rr = 0; rr < 4; ++rr)
                    o[rr] = fmaxf(fmaf(outacc[mt][ct][rr], sn, sh), 0.f);
                *(f32x4*)&out[(((size_t)n * 64 + c) * HH + hrow) * WW + wc0] = o;
            }
        }
    }
}

extern "C" void kernel_launch(void* const* d_in, const int* in_sizes, int n_in,
                              void* d_out, int out_size, void* d_ws, size_t ws_size,
                              hipStream_t stream) {
    const float* y    = (const float*)d_in[0];
    const float* x    = (const float*)d_in[1];
    const float* dw0  = (const float*)d_in[2];
    const float* g0   = (const float*)d_in[3];
    const float* b0   = (const float*)d_in[4];
    const float* m0   = (const float*)d_in[5];
    const float* v0   = (const float*)d_in[6];
    const float* pw0  = (const float*)d_in[7];
    const float* pwb0 = (const float*)d_in[8];
    const float* dw1  = (const float*)d_in[9];
    const float* g1   = (const float*)d_in[10];
    const float* b1   = (const float*)d_in[11];
    const float* m1   = (const float*)d_in[12];
    const float* v1   = (const float*)d_in[13];
    const float* pw1  = (const float*)d_in[14];
    const float* pwb1 = (const float*)d_in[15];
    const float* ng   = (const float*)d_in[16];
    const float* nb   = (const float*)d_in[17];
    const float* nm   = (const float*)d_in[18];
    const float* nv   = (const float*)d_in[19];

    unsigned short* wF = (unsigned short*)d_ws;   // 294912 B

    prep_w_kernel<<<72, 256, 0, stream>>>(pw0, pw1, wF);
    fused_kernel<<<800, 256, 0, stream>>>(y, x,
                                          dw0, g0, b0, m0, v0, pwb0,
                                          dw1, g1, b1, m1, v1, pwb1,
                                          ng, nb, nm, nv, wF, (float*)d_out);
}